// Round 5
// baseline (291.301 us; speedup 1.0000x reference)
//
#include <hip/hip_runtime.h>
#include <float.h>

#define EMBED   64
#define CODES   4096
#define NROWS   65536      // 512*8192/64
#define NELEM   4194304    // 512*8192
#define BR      128        // rows per block (4 waves x 32 rows)
#define NTILE   128        // 32-code tiles
#define TUNITS  512        // 16B fragment units per tile (4 kk x 2 split x 64 lanes)

typedef __attribute__((ext_vector_type(8)))  short bf16x8;   // 8 bf16 in 4 VGPRs
typedef __attribute__((ext_vector_type(16))) float f32x16;   // MFMA 32x32 accumulator

__device__ inline unsigned short f2bf(float f) {             // RNE float->bf16
    unsigned u = __float_as_uint(f);
    u += 0x7fff + ((u >> 16) & 1);
    return (unsigned short)(u >> 16);
}
__device__ inline float bf2f(unsigned short h) {
    return __uint_as_float(((unsigned)h) << 16);
}

// ws layout: [0,16K) cbuf; [16K] double accum; [32K,32K+1M) packed B-frags; +1M ET
// One fused setup kernel: blocks 0..15 cbuf(+accum), 16..143 pack, 144..399 ET.
__global__ void vq_setup(const float* __restrict__ E, float* __restrict__ cbuf,
                         double* __restrict__ accum, bf16x8* __restrict__ packed,
                         float* __restrict__ ET) {
    const int b = blockIdx.x, t = threadIdx.x;
    if (b < 16) {
        // cbuf: emulate np.sum(E*E, axis=0) (C-order: sequential over i, mul/add rounded)
        int j = b * 256 + t;
        float v = E[j];
        float s = __fmul_rn(v, v);
        for (int i = 1; i < EMBED; ++i) {
            v = E[(size_t)i * CODES + j];
            s = __fadd_rn(s, __fmul_rn(v, v));
        }
        cbuf[j] = s;
        if (j == 0) *accum = 0.0;           // d_ws poisoned 0xAA before every launch
    } else if (b < 144) {
        // pack E into MFMA B-fragment order (both splits per thread)
        int id = (b - 16) * 256 + t;        // [0, 32768)
        int lam = id & 63, kk = (id >> 6) & 3, g = id >> 8;
        int n  = g * 32 + (lam & 31);
        int kb = kk * 16 + (lam >> 5) * 8;
        bf16x8 vh, vl;
#pragma unroll
        for (int j = 0; j < 8; ++j) {
            float e = E[(size_t)(kb + j) * CODES + n];
            unsigned short hi = f2bf(e);
            vh[j] = (short)hi;
            vl[j] = (short)f2bf(e - bf2f(hi));
        }
        packed[((g * 4 + kk) * 2 + 0) * 64 + lam] = vh;
        packed[((g * 4 + kk) * 2 + 1) * 64 + lam] = vl;
    } else {
        // ET = E^T (fp32) for the coalesced output gather
        int id = (b - 144) * 256 + t;       // [0, 65536)
        int j = id >> 4, i0 = (id & 15) * 4;
        float4 v;
        v.x = E[(size_t)(i0 + 0) * CODES + j];
        v.y = E[(size_t)(i0 + 1) * CODES + j];
        v.z = E[(size_t)(i0 + 2) * CODES + j];
        v.w = E[(size_t)(i0 + 3) * CODES + j];
        *(float4*)(ET + (size_t)j * EMBED + i0) = v;
    }
}

template <bool PRE>
__global__ __launch_bounds__(256, 2)
void vq_main(const float* __restrict__ X, const float* __restrict__ E,
             const float* __restrict__ cbuf, const bf16x8* __restrict__ packed,
             const float* __restrict__ ET, double* __restrict__ accum,
             float* __restrict__ out) {
    __shared__ float rowm1[BR], rowsq[BR];
    __shared__ int   rowidx[BR], rowflg[BR];
    __shared__ float fredv[256];
    __shared__ int   fredi[256];

    const int t  = threadIdx.x;
    const int l  = t & 63, wv = t >> 6;
    const int m  = l & 31, h  = l >> 5;
    const int row0 = blockIdx.x * BR;

    // ---- A fragments (persistent): x split hi/lo; row ||x||^2 in reg ----
    bf16x8 ah[4], al[4];
    float sqreg;
    {
        const float* xrow = X + (size_t)(row0 + wv * 32 + m) * EMBED;
        float sq = 0.f;
#pragma unroll
        for (int kk = 0; kk < 4; ++kk) {
            int kb = kk * 16 + h * 8;
            float4 v0 = *(const float4*)(xrow + kb);
            float4 v1 = *(const float4*)(xrow + kb + 4);
            float xv[8] = {v0.x, v0.y, v0.z, v0.w, v1.x, v1.y, v1.z, v1.w};
#pragma unroll
            for (int j = 0; j < 8; ++j) {
                sq = fmaf(xv[j], xv[j], sq);
                unsigned short hi = f2bf(xv[j]);
                float r = xv[j] - bf2f(hi);
                ah[kk][j] = (short)hi;
                al[kk][j] = (short)f2bf(r);
            }
        }
        sq += __shfl_xor(sq, 32, 64);          // lanes l and l+32 hold same row
        sqreg = sq;
    }

    // top-2 of a = x.e - c/2 (max); tile index packed into low 7 mantissa bits
    float M1[16], M2[16];
#pragma unroll
    for (int e = 0; e < 16; ++e) { M1[e] = -FLT_MAX; M2[e] = -FLT_MAX; }

    auto process = [&](const bf16x8 (&B)[8], float nc, int g) {
        f32x16 acc;
#pragma unroll
        for (int e = 0; e < 16; ++e) acc[e] = nc;
#pragma unroll
        for (int kk = 0; kk < 4; ++kk) {
            acc = __builtin_amdgcn_mfma_f32_32x32x16_bf16(ah[kk], B[kk * 2],     acc, 0, 0, 0);
            acc = __builtin_amdgcn_mfma_f32_32x32x16_bf16(ah[kk], B[kk * 2 + 1], acc, 0, 0, 0);
            acc = __builtin_amdgcn_mfma_f32_32x32x16_bf16(al[kk], B[kk * 2],     acc, 0, 0, 0);
        }
        unsigned gu = (unsigned)g;
#pragma unroll
        for (int e = 0; e < 16; ++e) {
            float ap = __uint_as_float((__float_as_uint(acc[e]) & 0xFFFFFF80u) | gu);
            float m1o = M1[e];
            M1[e] = fmaxf(m1o, ap);
            M2[e] = __builtin_amdgcn_fmed3f(m1o, M2[e], ap);  // top-2 update
        }
    };

    if constexpr (PRE) {
        // barrier-free: stream packed B with 2-tile register double-buffer
        bf16x8 Ba[8], Bb[8];
        float ncA, ncB;
        {
            const bf16x8* p = packed + l;
#pragma unroll
            for (int q = 0; q < 8; ++q) Ba[q] = p[q * 64];
            ncA = -0.5f * cbuf[m];
        }
#pragma unroll 1
        for (int g = 0; g < NTILE; g += 2) {
            {   // prefetch tile g+1
                const bf16x8* p = packed + (size_t)(g + 1) * TUNITS + l;
#pragma unroll
                for (int q = 0; q < 8; ++q) Bb[q] = p[q * 64];
                ncB = -0.5f * cbuf[(g + 1) * 32 + m];
            }
            process(Ba, ncA, g);
            if (g + 2 < NTILE) {   // prefetch tile g+2
                const bf16x8* p = packed + (size_t)(g + 2) * TUNITS + l;
#pragma unroll
                for (int q = 0; q < 8; ++q) Ba[q] = p[q * 64];
                ncA = -0.5f * cbuf[(g + 2) * 32 + m];
            }
            process(Bb, ncB, g + 1);
        }
    } else {
        // fallback path (no workspace): convert E on the fly per tile
#pragma unroll 1
        for (int g = 0; g < NTILE; ++g) {
            bf16x8 B[8];
            int n = g * 32 + m;
#pragma unroll
            for (int kk = 0; kk < 4; ++kk) {
                const float* ec = E + (size_t)(kk * 16 + h * 8) * CODES + n;
                bf16x8 vh, vl;
#pragma unroll
                for (int j = 0; j < 8; ++j) {
                    float e = ec[(size_t)j * CODES];
                    unsigned short hi = f2bf(e);
                    vh[j] = (short)hi;
                    vl[j] = (short)f2bf(e - bf2f(hi));
                }
                B[kk * 2] = vh; B[kk * 2 + 1] = vl;
            }
            process(B, -0.5f * cbuf[g * 32 + m], g);
        }
    }

    // extract indices from packed scores, then cross-lane top-2 merge
    int I1[16];
#pragma unroll
    for (int e = 0; e < 16; ++e)
        I1[e] = (int)(((__float_as_uint(M1[e]) & 0x7Fu) << 5) | (unsigned)m);
#pragma unroll
    for (int d = 1; d < 32; d <<= 1) {
#pragma unroll
        for (int e = 0; e < 16; ++e) {
            float oM1 = __shfl_xor(M1[e], d, 64);
            float oM2 = __shfl_xor(M2[e], d, 64);
            int   oI  = __shfl_xor(I1[e], d, 64);
            float lo  = fminf(M1[e], oM1);
            M2[e] = fmaxf(lo, fmaxf(M2[e], oM2));
            bool c = oM1 > M1[e];
            I1[e] = c ? oI : I1[e];
            M1[e] = c ? oM1 : M1[e];
        }
    }
    if (h == 0) rowsq[wv * 32 + m] = sqreg;
    // C/D row = (reg&3) + 8*(reg>>2) + 4*(lane>>5); one lane writes each row
#pragma unroll
    for (int e = 0; e < 16; ++e) {
        int r = (e & 3) + 8 * (e >> 2) + 4 * h;
        if (m == r) {
            rowm1[wv * 32 + r]  = __uint_as_float(__float_as_uint(M1[e]) & 0xFFFFFF80u);
            rowidx[wv * 32 + r] = I1[e];
            rowflg[wv * 32 + r] = (2.f * (M1[e] - M2[e]) < 2e-4f) ? 1 : 0;
        }
    }
    __syncthreads();

    // ---- rare fallback: bit-exact fp32 numpy-reference emulation (uniform branch) ----
#pragma unroll 1
    for (int r = 0; r < BR; ++r) {
        if (rowflg[r] == 0) continue;
        const float* xr = X + (size_t)(row0 + r) * EMBED;
        float racc[8];
#pragma unroll
        for (int jq = 0; jq < 8; ++jq) racc[jq] = __fmul_rn(xr[jq], xr[jq]);
#pragma unroll
        for (int i = 8; i < 64; i += 8)
#pragma unroll
            for (int jq = 0; jq < 8; ++jq)
                racc[jq] = __fadd_rn(racc[jq], __fmul_rn(xr[i + jq], xr[i + jq]));
        float A = __fadd_rn(
            __fadd_rn(__fadd_rn(racc[0], racc[1]), __fadd_rn(racc[2], racc[3])),
            __fadd_rn(__fadd_rn(racc[4], racc[5]), __fadd_rn(racc[6], racc[7])));

        float best = FLT_MAX; int bestj = CODES;
#pragma unroll 1
        for (int jj = 0; jj < 16; ++jj) {
            int j = jj * 256 + t;
            float mm = 0.f;
#pragma unroll
            for (int i = 0; i < 64; ++i)
                mm = fmaf(xr[i], E[(size_t)i * CODES + j], mm);  // sequential FMA (BLAS k-loop)
            float d = __fadd_rn(__fsub_rn(A, __fmul_rn(2.f, mm)), cbuf[j]);
            if (d < best || (d == best && j < bestj)) { best = d; bestj = j; }
        }
        fredv[t] = best; fredi[t] = bestj;
        __syncthreads();
        if (t == 0) {
            float B = fredv[0]; int BI = fredi[0];
            for (int c2 = 1; c2 < 256; ++c2) {
                float dc = fredv[c2]; int jc = fredi[c2];
                if (dc < B || (dc == B && jc < BI)) { B = dc; BI = jc; }
            }
            rowidx[r] = BI;
        }
        __syncthreads();
    }

    // ---- outputs ----
    if (t < BR) out[(size_t)NELEM + 1 + row0 + t] = (float)rowidx[t];  // idx as float
    if (t == 0) {
        float bs = 0.f;
        for (int r = 0; r < BR; ++r) bs += rowsq[r] - 2.f * rowm1[r];  // sum (x-e)^2
        atomicAdd(accum, (double)bs);
    }
    {
        int r = t >> 1, i0 = (t & 1) * 32;
        int j = rowidx[r];
        float* dst = out + (size_t)(row0 + r) * EMBED + i0;
        if constexpr (PRE) {
            const float* src = ET + (size_t)j * EMBED + i0;
#pragma unroll
            for (int g = 0; g < 8; ++g)
                *(float4*)(dst + g * 4) = *(const float4*)(src + g * 4);
        } else {
#pragma unroll
            for (int g = 0; g < 8; ++g) {
                float4 v;
                v.x = E[(size_t)(i0 + g * 4 + 0) * CODES + j];
                v.y = E[(size_t)(i0 + g * 4 + 1) * CODES + j];
                v.z = E[(size_t)(i0 + g * 4 + 2) * CODES + j];
                v.w = E[(size_t)(i0 + g * 4 + 3) * CODES + j];
                *(float4*)(dst + g * 4) = v;
            }
        }
    }
}

__global__ void vq_finalize(const double* __restrict__ accum, float* __restrict__ out) {
    out[NELEM] = (float)(0.25 * (*accum) / (double)NELEM);
}

extern "C" void kernel_launch(void* const* d_in, const int* in_sizes, int n_in,
                              void* d_out, int out_size, void* d_ws, size_t ws_size,
                              hipStream_t stream) {
    const float* X = (const float*)d_in[0];   // (512, 8192, 1) f32 -> 65536 rows x 64
    const float* E = (const float*)d_in[1];   // (64, 4096) f32 row-major
    float* out = (float*)d_out;
    float*  cbuf   = (float*)d_ws;
    double* accum  = (double*)((char*)d_ws + 16384);
    bf16x8* packed = (bf16x8*)((char*)d_ws + 32768);
    float*  ET     = (float*)((char*)d_ws + 32768 + 1048576);
    const size_t need = 32768 + 1048576 + 1048576;
    const bool pre = (ws_size >= need);       // constant across calls -> same work every call

    vq_setup<<<pre ? 400 : 16, 256, 0, stream>>>(E, cbuf, accum, packed, ET);
    if (pre)
        vq_main<true><<<NROWS / BR, 256, 0, stream>>>(X, E, cbuf, packed, ET, accum, out);
    else
        vq_main<false><<<NROWS / BR, 256, 0, stream>>>(X, E, cbuf, packed, ET, accum, out);
    vq_finalize<<<1, 1, 0, stream>>>(accum, out);
}

// Round 6
// 261.953 us; speedup vs baseline: 1.1120x; 1.1120x over previous
//
#include <hip/hip_runtime.h>
#include <float.h>

#define EMBED   64
#define CODES   4096
#define NROWS   65536      // 512*8192/64
#define NELEM   4194304    // 512*8192
#define BR      128        // rows per block (4 waves x 32 rows)
#define CCH     128        // codes per chunk (4 tiles of 32)
#define NCH     32         // chunks
#define CUNITS  2048       // 16B fragment units per chunk
#define NTILE   128        // 32-code tiles total

typedef __attribute__((ext_vector_type(8)))  short bf16x8;   // 8 bf16 in 4 VGPRs
typedef __attribute__((ext_vector_type(16))) float f32x16;   // MFMA 32x32 accumulator

__device__ inline unsigned short f2bf(float f) {             // RNE float->bf16
    unsigned u = __float_as_uint(f);
    u += 0x7fff + ((u >> 16) & 1);
    return (unsigned short)(u >> 16);
}
__device__ inline float bf2f(unsigned short h) {
    return __uint_as_float(((unsigned)h) << 16);
}

// ws layout: [0,16K) cbuf; [16K] double accum; [32K,32K+1M) packed B-frags; +1M ET
// Fused setup: blocks 0..15 cbuf(+accum), 16..143 pack, 144..399 ET.
__global__ void vq_setup(const float* __restrict__ E, float* __restrict__ cbuf,
                         double* __restrict__ accum, bf16x8* __restrict__ packed,
                         float* __restrict__ ET) {
    const int b = blockIdx.x, t = threadIdx.x;
    if (b < 16) {
        // cbuf: emulate np.sum(E*E, axis=0) (C-order: sequential i, mul/add rounded)
        int j = b * 256 + t;
        float v = E[j];
        float s = __fmul_rn(v, v);
        for (int i = 1; i < EMBED; ++i) {
            v = E[(size_t)i * CODES + j];
            s = __fadd_rn(s, __fmul_rn(v, v));
        }
        cbuf[j] = s;
        if (j == 0) *accum = 0.0;           // d_ws poisoned 0xAA before every launch
    } else if (b < 144) {
        // pack E into MFMA B-fragment order (both splits per thread)
        int id = (b - 16) * 256 + t;        // [0, 32768)
        int lam = id & 63, kk = (id >> 6) & 3, g = id >> 8;
        int n  = g * 32 + (lam & 31);
        int kb = kk * 16 + (lam >> 5) * 8;
        bf16x8 vh, vl;
#pragma unroll
        for (int j = 0; j < 8; ++j) {
            float e = E[(size_t)(kb + j) * CODES + n];
            unsigned short hi = f2bf(e);
            vh[j] = (short)hi;
            vl[j] = (short)f2bf(e - bf2f(hi));
        }
        packed[((g * 4 + kk) * 2 + 0) * 64 + lam] = vh;
        packed[((g * 4 + kk) * 2 + 1) * 64 + lam] = vl;
    } else {
        // ET = E^T (fp32) for the coalesced output gather
        int id = (b - 144) * 256 + t;       // [0, 65536)
        int j = id >> 4, i0 = (id & 15) * 4;
        float4 v;
        v.x = E[(size_t)(i0 + 0) * CODES + j];
        v.y = E[(size_t)(i0 + 1) * CODES + j];
        v.z = E[(size_t)(i0 + 2) * CODES + j];
        v.w = E[(size_t)(i0 + 3) * CODES + j];
        *(float4*)(ET + (size_t)j * EMBED + i0) = v;
    }
}

template <bool PRE>
__global__ __launch_bounds__(256, 2)
void vq_main(const float* __restrict__ X, const float* __restrict__ E,
             const float* __restrict__ cbuf, const bf16x8* __restrict__ packed,
             const float* __restrict__ ET, double* __restrict__ accum,
             float* __restrict__ out) {
    __shared__ bf16x8 lbuf[2][CUNITS];      // 64 KB; scratch overlays after the loop

    const int t  = threadIdx.x;
    const int l  = t & 63, wv = t >> 6;
    const int m  = l & 31, h  = l >> 5;
    const int row0 = blockIdx.x * BR;

    // ---- A fragments (persistent): x split hi/lo; row ||x||^2 in reg ----
    bf16x8 ah[4], al[4];
    float sqreg;
    {
        const float* xrow = X + (size_t)(row0 + wv * 32 + m) * EMBED;
        float sq = 0.f;
#pragma unroll
        for (int kk = 0; kk < 4; ++kk) {
            int kb = kk * 16 + h * 8;
            float4 v0 = *(const float4*)(xrow + kb);
            float4 v1 = *(const float4*)(xrow + kb + 4);
            float xv[8] = {v0.x, v0.y, v0.z, v0.w, v1.x, v1.y, v1.z, v1.w};
#pragma unroll
            for (int j = 0; j < 8; ++j) {
                sq = fmaf(xv[j], xv[j], sq);
                unsigned short hi = f2bf(xv[j]);
                float r = xv[j] - bf2f(hi);
                ah[kk][j] = (short)hi;
                al[kk][j] = (short)f2bf(r);
            }
        }
        sq += __shfl_xor(sq, 32, 64);       // lanes l and l+32 hold same row
        sqreg = sq;
    }

    // top-2 of a = x.e - c/2 (max); tile index packed into low 7 mantissa bits
    float M1[16], M2[16];
#pragma unroll
    for (int e = 0; e < 16; ++e) { M1[e] = -FLT_MAX; M2[e] = -FLT_MAX; }

    auto epi = [&](const f32x16& a, int g) {      // 3 VALU per element
        unsigned gu = (unsigned)g;
#pragma unroll
        for (int e = 0; e < 16; ++e) {
            float ap = __uint_as_float((__float_as_uint(a[e]) & 0xFFFFFF80u) | gu);
            float m1o = M1[e];
            M1[e] = fmaxf(m1o, ap);
            M2[e] = __builtin_amdgcn_fmed3f(m1o, M2[e], ap);
        }
    };

    if constexpr (PRE) {
        auto stage = [&](int ch, int buf) {       // async global->LDS, no VGPR round-trip
#pragma unroll
            for (int q = 0; q < 8; ++q) {
                const bf16x8* gp = packed + (size_t)ch * CUNITS + q * 256 + t;
                bf16x8* lp = &lbuf[buf][q * 256 + wv * 64];  // wave-uniform base +lane*16
                __builtin_amdgcn_global_load_lds(
                    (const __attribute__((address_space(1))) void*)gp,
                    (__attribute__((address_space(3))) void*)lp, 16, 0, 0);
            }
        };

        // software pipeline: prev-pair accumulators, epilogue delayed by one pair
        f32x16 pA, pB; int pGA = 0, pGB = 0;
#pragma unroll
        for (int e = 0; e < 16; ++e) { pA[e] = -FLT_MAX; pB[e] = -FLT_MAX; }  // harmless dummy

        const int ch0 = blockIdx.x & (NCH - 1);   // rotate chunk order across blocks
        stage(ch0, 0);
        __syncthreads();

        int b = 0;
#pragma unroll 1
        for (int cc = 0; cc < NCH; ++cc) {
            int ch = ch0 + cc; if (ch >= NCH) ch -= NCH;
            if (cc + 1 < NCH) { int cn = ch + 1; if (cn >= NCH) cn -= NCH; stage(cn, b ^ 1); }
            const bf16x8* lb = lbuf[b];
#pragma unroll
            for (int pp = 0; pp < 2; ++pp) {
                const int tl0 = pp * 2, tl1 = tl0 + 1;
                const int g0 = ch * 4 + tl0, g1 = ch * 4 + tl1;
                // issue LDS reads for this pair
                bf16x8 B0[8], B1[8];
#pragma unroll
                for (int kk = 0; kk < 4; ++kk) {
                    B0[kk * 2]     = lb[tl0 * 512 + kk * 128 + l];
                    B0[kk * 2 + 1] = lb[tl0 * 512 + kk * 128 + 64 + l];
                    B1[kk * 2]     = lb[tl1 * 512 + kk * 128 + l];
                    B1[kk * 2 + 1] = lb[tl1 * 512 + kk * 128 + 64 + l];
                }
                float nc0 = -0.5f * cbuf[g0 * 32 + m];
                float nc1 = -0.5f * cbuf[g1 * 32 + m];
                // delayed epilogue of previous pair: independent VALU, fills
                // the lgkm shadow and co-issues with MFMA
                epi(pA, pGA);
                epi(pB, pGB);
                f32x16 a0, a1;
#pragma unroll
                for (int e = 0; e < 16; ++e) { a0[e] = nc0; a1[e] = nc1; }
#pragma unroll
                for (int kk = 0; kk < 4; ++kk) {  // two interleaved chains, gap 2
                    a0 = __builtin_amdgcn_mfma_f32_32x32x16_bf16(ah[kk], B0[kk * 2],     a0, 0, 0, 0);
                    a1 = __builtin_amdgcn_mfma_f32_32x32x16_bf16(ah[kk], B1[kk * 2],     a1, 0, 0, 0);
                    a0 = __builtin_amdgcn_mfma_f32_32x32x16_bf16(ah[kk], B0[kk * 2 + 1], a0, 0, 0, 0);
                    a1 = __builtin_amdgcn_mfma_f32_32x32x16_bf16(ah[kk], B1[kk * 2 + 1], a1, 0, 0, 0);
                    a0 = __builtin_amdgcn_mfma_f32_32x32x16_bf16(al[kk], B0[kk * 2],     a0, 0, 0, 0);
                    a1 = __builtin_amdgcn_mfma_f32_32x32x16_bf16(al[kk], B1[kk * 2],     a1, 0, 0, 0);
                }
                pA = a0; pB = a1; pGA = g0; pGB = g1;
            }
            __syncthreads();
            b ^= 1;
        }
        epi(pA, pGA);
        epi(pB, pGB);
    } else {
        // fallback path (no workspace): convert E on the fly per tile
#pragma unroll 1
        for (int g = 0; g < NTILE; ++g) {
            bf16x8 B[8];
            int n = g * 32 + m;
#pragma unroll
            for (int kk = 0; kk < 4; ++kk) {
                const float* ec = E + (size_t)(kk * 16 + h * 8) * CODES + n;
                bf16x8 vh, vl;
#pragma unroll
                for (int j = 0; j < 8; ++j) {
                    float e = ec[(size_t)j * CODES];
                    unsigned short hi = f2bf(e);
                    vh[j] = (short)hi;
                    vl[j] = (short)f2bf(e - bf2f(hi));
                }
                B[kk * 2] = vh; B[kk * 2 + 1] = vl;
            }
            float nc = -0.5f * cbuf[g * 32 + m];
            f32x16 acc;
#pragma unroll
            for (int e = 0; e < 16; ++e) acc[e] = nc;
#pragma unroll
            for (int kk = 0; kk < 4; ++kk) {
                acc = __builtin_amdgcn_mfma_f32_32x32x16_bf16(ah[kk], B[kk * 2],     acc, 0, 0, 0);
                acc = __builtin_amdgcn_mfma_f32_32x32x16_bf16(ah[kk], B[kk * 2 + 1], acc, 0, 0, 0);
                acc = __builtin_amdgcn_mfma_f32_32x32x16_bf16(al[kk], B[kk * 2],     acc, 0, 0, 0);
            }
            epi(acc, g);
        }
        __syncthreads();
    }

    // lbuf dead -> overlay scratch
    float* rowm1  = (float*)&lbuf[0][0];
    float* rowsq  = rowm1 + BR;
    int*   rowidx = (int*)(rowsq + BR);
    int*   rowflg = rowidx + BR;
    float* fredv  = (float*)(rowflg + BR);
    int*   fredi  = (int*)(fredv + 256);

    // extract indices from packed scores, then cross-lane top-2 merge
    int I1[16];
#pragma unroll
    for (int e = 0; e < 16; ++e)
        I1[e] = (int)(((__float_as_uint(M1[e]) & 0x7Fu) << 5) | (unsigned)m);
#pragma unroll
    for (int d = 1; d < 32; d <<= 1) {
#pragma unroll
        for (int e = 0; e < 16; ++e) {
            float oM1 = __shfl_xor(M1[e], d, 64);
            float oM2 = __shfl_xor(M2[e], d, 64);
            int   oI  = __shfl_xor(I1[e], d, 64);
            float lo  = fminf(M1[e], oM1);
            M2[e] = fmaxf(lo, fmaxf(M2[e], oM2));
            bool c = oM1 > M1[e];
            I1[e] = c ? oI : I1[e];
            M1[e] = c ? oM1 : M1[e];
        }
    }
    if (h == 0) rowsq[wv * 32 + m] = sqreg;
    // C/D row = (reg&3) + 8*(reg>>2) + 4*(lane>>5); one lane writes each row
#pragma unroll
    for (int e = 0; e < 16; ++e) {
        int r = (e & 3) + 8 * (e >> 2) + 4 * h;
        if (m == r) {
            rowm1[wv * 32 + r]  = __uint_as_float(__float_as_uint(M1[e]) & 0xFFFFFF80u);
            rowidx[wv * 32 + r] = I1[e];
            rowflg[wv * 32 + r] = (2.f * (M1[e] - M2[e]) < 2e-4f) ? 1 : 0;
        }
    }
    __syncthreads();

    // ---- rare fallback: bit-exact fp32 numpy-reference emulation (uniform branch) ----
#pragma unroll 1
    for (int r = 0; r < BR; ++r) {
        if (rowflg[r] == 0) continue;
        const float* xr = X + (size_t)(row0 + r) * EMBED;
        float racc[8];
#pragma unroll
        for (int jq = 0; jq < 8; ++jq) racc[jq] = __fmul_rn(xr[jq], xr[jq]);
#pragma unroll
        for (int i = 8; i < 64; i += 8)
#pragma unroll
            for (int jq = 0; jq < 8; ++jq)
                racc[jq] = __fadd_rn(racc[jq], __fmul_rn(xr[i + jq], xr[i + jq]));
        float A = __fadd_rn(
            __fadd_rn(__fadd_rn(racc[0], racc[1]), __fadd_rn(racc[2], racc[3])),
            __fadd_rn(__fadd_rn(racc[4], racc[5]), __fadd_rn(racc[6], racc[7])));

        float best = FLT_MAX; int bestj = CODES;
#pragma unroll 1
        for (int jj = 0; jj < 16; ++jj) {
            int j = jj * 256 + t;
            float mm = 0.f;
#pragma unroll
            for (int i = 0; i < 64; ++i)
                mm = fmaf(xr[i], E[(size_t)i * CODES + j], mm);  // sequential FMA (BLAS k-loop)
            float d = __fadd_rn(__fsub_rn(A, __fmul_rn(2.f, mm)), cbuf[j]);
            if (d < best || (d == best && j < bestj)) { best = d; bestj = j; }
        }
        fredv[t] = best; fredi[t] = bestj;
        __syncthreads();
        if (t == 0) {
            float B = fredv[0]; int BI = fredi[0];
            for (int c2 = 1; c2 < 256; ++c2) {
                float dc = fredv[c2]; int jc = fredi[c2];
                if (dc < B || (dc == B && jc < BI)) { B = dc; BI = jc; }
            }
            rowidx[r] = BI;
        }
        __syncthreads();
    }

    // ---- outputs ----
    if (t < BR) out[(size_t)NELEM + 1 + row0 + t] = (float)rowidx[t];  // idx as float
    if (t == 0) {
        float bs = 0.f;
        for (int r = 0; r < BR; ++r) bs += rowsq[r] - 2.f * rowm1[r];  // sum (x-e)^2
        atomicAdd(accum, (double)bs);
    }
    {
        int r = t >> 1, i0 = (t & 1) * 32;
        int j = rowidx[r];
        float* dst = out + (size_t)(row0 + r) * EMBED + i0;
        if constexpr (PRE) {
            const float* src = ET + (size_t)j * EMBED + i0;
#pragma unroll
            for (int g = 0; g < 8; ++g)
                *(float4*)(dst + g * 4) = *(const float4*)(src + g * 4);
        } else {
#pragma unroll
            for (int g = 0; g < 8; ++g) {
                float4 v;
                v.x = E[(size_t)(i0 + g * 4 + 0) * CODES + j];
                v.y = E[(size_t)(i0 + g * 4 + 1) * CODES + j];
                v.z = E[(size_t)(i0 + g * 4 + 2) * CODES + j];
                v.w = E[(size_t)(i0 + g * 4 + 3) * CODES + j];
                *(float4*)(dst + g * 4) = v;
            }
        }
    }
}

__global__ void vq_finalize(const double* __restrict__ accum, float* __restrict__ out) {
    out[NELEM] = (float)(0.25 * (*accum) / (double)NELEM);
}

extern "C" void kernel_launch(void* const* d_in, const int* in_sizes, int n_in,
                              void* d_out, int out_size, void* d_ws, size_t ws_size,
                              hipStream_t stream) {
    const float* X = (const float*)d_in[0];   // (512, 8192, 1) f32 -> 65536 rows x 64
    const float* E = (const float*)d_in[1];   // (64, 4096) f32 row-major
    float* out = (float*)d_out;
    float*  cbuf   = (float*)d_ws;
    double* accum  = (double*)((char*)d_ws + 16384);
    bf16x8* packed = (bf16x8*)((char*)d_ws + 32768);
    float*  ET     = (float*)((char*)d_ws + 32768 + 1048576);
    const size_t need = 32768 + 1048576 + 1048576;
    const bool pre = (ws_size >= need);       // constant across calls -> same work every call

    vq_setup<<<pre ? 400 : 16, 256, 0, stream>>>(E, cbuf, accum, packed, ET);
    if (pre)
        vq_main<true><<<NROWS / BR, 256, 0, stream>>>(X, E, cbuf, packed, ET, accum, out);
    else
        vq_main<false><<<NROWS / BR, 256, 0, stream>>>(X, E, cbuf, packed, ET, accum, out);
    vq_finalize<<<1, 1, 0, stream>>>(accum, out);
}